// Round 5
// baseline (64.535 us; speedup 1.0000x reference)
//
#include <hip/hip_runtime.h>

#define D_DIM 4096
#define EPSF 1e-8f

typedef float f32x4 __attribute__((ext_vector_type(4)));

// Two rows per wave: 64 lanes x 16 float4 per tensor per row, two rows'
// accumulations interleaved so loads stream continuously across the row
// boundary (no per-row load->reduce drain). No barriers, no LDS.
__global__ __launch_bounds__(256) void cosim_rows(const float* __restrict__ q,
                                                  const float* __restrict__ a,
                                                  float* __restrict__ cosv) {
    const int wid  = (blockIdx.x * 256 + threadIdx.x) >> 6;   // global wave id
    const int lane = threadIdx.x & 63;
    const int row0 = wid * 2;
    const int row1 = row0 + 1;

    const f32x4* q0 = reinterpret_cast<const f32x4*>(q + (size_t)row0 * D_DIM);
    const f32x4* a0 = reinterpret_cast<const f32x4*>(a + (size_t)row0 * D_DIM);
    const f32x4* q1 = reinterpret_cast<const f32x4*>(q + (size_t)row1 * D_DIM);
    const f32x4* a1 = reinterpret_cast<const f32x4*>(a + (size_t)row1 * D_DIM);

    float dot0 = 0.f, qq0 = 0.f, aa0 = 0.f;
    float dot1 = 0.f, qq1 = 0.f, aa1 = 0.f;
#pragma unroll
    for (int k = 0; k < 16; ++k) {
        f32x4 vq0 = q0[lane + k * 64];
        f32x4 va0 = a0[lane + k * 64];
        f32x4 vq1 = q1[lane + k * 64];
        f32x4 va1 = a1[lane + k * 64];
        dot0 += vq0.x * va0.x + vq0.y * va0.y + vq0.z * va0.z + vq0.w * va0.w;
        qq0  += vq0.x * vq0.x + vq0.y * vq0.y + vq0.z * vq0.z + vq0.w * vq0.w;
        aa0  += va0.x * va0.x + va0.y * va0.y + va0.z * va0.z + va0.w * va0.w;
        dot1 += vq1.x * va1.x + vq1.y * va1.y + vq1.z * va1.z + vq1.w * va1.w;
        qq1  += vq1.x * vq1.x + vq1.y * vq1.y + vq1.z * vq1.z + vq1.w * vq1.w;
        aa1  += va1.x * va1.x + va1.y * va1.y + va1.z * va1.z + va1.w * va1.w;
    }

    // wave64 down-reduce for both rows; lane 0 holds the sums
#pragma unroll
    for (int off = 32; off > 0; off >>= 1) {
        dot0 += __shfl_down(dot0, off, 64);
        qq0  += __shfl_down(qq0,  off, 64);
        aa0  += __shfl_down(aa0,  off, 64);
        dot1 += __shfl_down(dot1, off, 64);
        qq1  += __shfl_down(qq1,  off, 64);
        aa1  += __shfl_down(aa1,  off, 64);
    }

    if (lane == 0) {
        float qn0 = fmaxf(sqrtf(qq0), EPSF);
        float an0 = fmaxf(sqrtf(aa0), EPSF);
        cosv[row0] = dot0 / (qn0 * an0);
        float qn1 = fmaxf(sqrtf(qq1), EPSF);
        float an1 = fmaxf(sqrtf(aa1), EPSF);
        cosv[row1] = dot1 / (qn1 * an1);
    }
}

// Single block: deterministic fixed-order reduction of cos values by label.
__global__ __launch_bounds__(256) void cosim_finalize(const float* __restrict__ cosv,
                                                      const int* __restrict__ label,
                                                      const float* __restrict__ margin,
                                                      float* __restrict__ out, int B) {
    const int t = threadIdx.x;
    float ts = 0.f, fs = 0.f, tc = 0.f, fc = 0.f;
    for (int i = t; i < B; i += 256) {
        float c = cosv[i];
        int l = label[i];
        if (l == 1)       { ts += c; tc += 1.f; }
        else if (l == -1) { fs += c; fc += 1.f; }
    }
#pragma unroll
    for (int off = 32; off > 0; off >>= 1) {
        ts += __shfl_down(ts, off, 64);
        fs += __shfl_down(fs, off, 64);
        tc += __shfl_down(tc, off, 64);
        fc += __shfl_down(fc, off, 64);
    }
    __shared__ float s[4][4];
    const int wave = t >> 6;
    if ((t & 63) == 0) { s[0][wave] = ts; s[1][wave] = fs; s[2][wave] = tc; s[3][wave] = fc; }
    __syncthreads();
    if (t == 0) {
        float tsum = s[0][0] + s[0][1] + s[0][2] + s[0][3];
        float fsum = s[1][0] + s[1][1] + s[1][2] + s[1][3];
        float tcnt = s[2][0] + s[2][1] + s[2][2] + s[2][3];
        float fcnt = s[3][0] + s[3][1] + s[3][2] + s[3][3];
        out[0] = fmaxf(0.f, margin[0] - tsum / tcnt + fsum / fcnt);
    }
}

extern "C" void kernel_launch(void* const* d_in, const int* in_sizes, int n_in,
                              void* d_out, int out_size, void* d_ws, size_t ws_size,
                              hipStream_t stream) {
    const float* ques   = (const float*)d_in[0];
    const float* ans    = (const float*)d_in[1];
    const int*   label  = (const int*)d_in[2];
    const float* margin = (const float*)d_in[3];
    float* out = (float*)d_out;

    const int B = in_sizes[2];          // 8192 rows
    float* cosv = (float*)d_ws;         // B floats of scratch

    // 2 rows per wave: 4096 waves / 4 waves per block = 1024 blocks
    cosim_rows<<<B / 8, 256, 0, stream>>>(ques, ans, cosv);
    cosim_finalize<<<1, 256, 0, stream>>>(cosv, label, margin, out, B);
}

// Round 6
// 59.864 us; speedup vs baseline: 1.0780x; 1.0780x over previous
//
#include <hip/hip_runtime.h>

#define D_DIM 4096
#define EPSF 1e-8f
#define NBINS 64

typedef float f32x4 __attribute__((ext_vector_type(4)));

// d_ws layout (all zeroed by hipMemsetAsync each launch):
//   float tbin[64]   @ byte 0
//   float fbin[64]   @ byte 256
//   uint  tcb [64]   @ byte 512
//   uint  fcb [64]   @ byte 768
//   uint  counter    @ byte 1024
//
// One wave per row (4 rows per 256-thread block). All cross-block traffic is
// device-scope atomic RMWs (coherence-point ops, no cache fences -> avoids the
// Round-2 threadfence disaster). The completion-counter add is data-dependent
// on the bin-atomics' returned values, so counter==N-1 implies all bins done.
__global__ __launch_bounds__(256) void cosim_fused(const float* __restrict__ q,
                                                   const float* __restrict__ a,
                                                   const int* __restrict__ label,
                                                   const float* __restrict__ margin,
                                                   float* __restrict__ tbin,
                                                   float* __restrict__ fbin,
                                                   unsigned* __restrict__ tcb,
                                                   unsigned* __restrict__ fcb,
                                                   unsigned* __restrict__ counter,
                                                   float* __restrict__ out) {
    const int t    = threadIdx.x;
    const int lane = t & 63;
    const int wave = t >> 6;
    const int row  = blockIdx.x * 4 + wave;

    const f32x4* q4 = reinterpret_cast<const f32x4*>(q + (size_t)row * D_DIM);
    const f32x4* a4 = reinterpret_cast<const f32x4*>(a + (size_t)row * D_DIM);

    float dot = 0.f, qq = 0.f, aa = 0.f;
#pragma unroll
    for (int k = 0; k < 16; ++k) {
        f32x4 vq = q4[lane + k * 64];
        f32x4 va = a4[lane + k * 64];
        dot += vq.x * va.x + vq.y * va.y + vq.z * va.z + vq.w * va.w;
        qq  += vq.x * vq.x + vq.y * vq.y + vq.z * vq.z + vq.w * vq.w;
        aa  += va.x * va.x + va.y * va.y + va.z * va.z + va.w * va.w;
    }

#pragma unroll
    for (int off = 32; off > 0; off >>= 1) {
        dot += __shfl_down(dot, off, 64);
        qq  += __shfl_down(qq,  off, 64);
        aa  += __shfl_down(aa,  off, 64);
    }

    __shared__ float    sh_t[4], sh_f[4];
    __shared__ unsigned sh_tc[4], sh_fc[4];
    __shared__ unsigned sh_prev;

    if (lane == 0) {
        float qn = fmaxf(sqrtf(qq), EPSF);
        float an = fmaxf(sqrtf(aa), EPSF);
        float c  = dot / (qn * an);
        int l = label[row];
        sh_t[wave]  = (l == 1)  ? c : 0.f;
        sh_f[wave]  = (l == -1) ? c : 0.f;
        sh_tc[wave] = (l == 1)  ? 1u : 0u;
        sh_fc[wave] = (l == -1) ? 1u : 0u;
    }
    __syncthreads();

    if (t == 0) {
        float    ts = sh_t[0] + sh_t[1] + sh_t[2] + sh_t[3];
        float    fs = sh_f[0] + sh_f[1] + sh_f[2] + sh_f[3];
        unsigned tc = sh_tc[0] + sh_tc[1] + sh_tc[2] + sh_tc[3];
        unsigned fc = sh_fc[0] + sh_fc[1] + sh_fc[2] + sh_fc[3];
        const int b = blockIdx.x & (NBINS - 1);
        float    o1 = atomicAdd(&tbin[b], ts);
        float    o2 = atomicAdd(&fbin[b], fs);
        unsigned o3 = atomicAdd(&tcb[b], tc);
        unsigned o4 = atomicAdd(&fcb[b], fc);
        // dep == 0 always, but opaque to the compiler: forces the counter RMW
        // to wait for the bin RMW responses (ordering without any fence).
        unsigned dep = __float_as_uint(o1) | __float_as_uint(o2) | o3 | o4;
        asm volatile("v_and_b32 %0, 0, %0" : "+v"(dep));
        sh_prev = atomicAdd(counter, 1u + dep);
    }
    __syncthreads();

    if (sh_prev == (unsigned)(gridDim.x - 1)) {
        // Last block: gather bins via RMW-reads (coherent), fixed-order reduce.
        float    tb = 0.f, fb = 0.f;
        unsigned tcv = 0u, fcv = 0u;
        if (t < NBINS) {
            tb  = atomicAdd(&tbin[t], 0.f);
            fb  = atomicAdd(&fbin[t], 0.f);
            tcv = atomicAdd(&tcb[t], 0u);
            fcv = atomicAdd(&fcb[t], 0u);
        }
        if (wave == 0) {
#pragma unroll
            for (int off = 32; off > 0; off >>= 1) {
                tb  += __shfl_down(tb,  off, 64);
                fb  += __shfl_down(fb,  off, 64);
                tcv += __shfl_down(tcv, off, 64);
                fcv += __shfl_down(fcv, off, 64);
            }
            if (t == 0) {
                float true_ave  = tb / (float)tcv;
                float false_ave = fb / (float)fcv;
                out[0] = fmaxf(0.f, margin[0] - true_ave + false_ave);
            }
        }
    }
}

extern "C" void kernel_launch(void* const* d_in, const int* in_sizes, int n_in,
                              void* d_out, int out_size, void* d_ws, size_t ws_size,
                              hipStream_t stream) {
    const float* ques   = (const float*)d_in[0];
    const float* ans    = (const float*)d_in[1];
    const int*   label  = (const int*)d_in[2];
    const float* margin = (const float*)d_in[3];
    float* out = (float*)d_out;

    const int B = in_sizes[2];                          // 8192 rows
    float*    tbin    = (float*)d_ws;                   // 64 floats
    float*    fbin    = (float*)((char*)d_ws + 256);    // 64 floats
    unsigned* tcb     = (unsigned*)((char*)d_ws + 512); // 64 uints
    unsigned* fcb     = (unsigned*)((char*)d_ws + 768); // 64 uints
    unsigned* counter = (unsigned*)((char*)d_ws + 1024);

    hipMemsetAsync(d_ws, 0, 1056, stream);
    // 1 wave per row, 4 rows per block -> B/4 = 2048 blocks
    cosim_fused<<<B / 4, 256, 0, stream>>>(ques, ans, label, margin,
                                           tbin, fbin, tcb, fcb, counter, out);
}

// Round 7
// 55.627 us; speedup vs baseline: 1.1601x; 1.0762x over previous
//
#include <hip/hip_runtime.h>

#define D_DIM 4096
#define EPSF 1e-8f
#define NBINS 64

typedef float f32x4 __attribute__((ext_vector_type(4)));

// d_ws layout (zeroed by hipMemsetAsync each launch):
//   float tbin[64]   @ byte 0
//   float fbin[64]   @ byte 256
//   uint  tcb [64]   @ byte 512
//   uint  fcb [64]   @ byte 768
//   uint  counter    @ byte 1024
//
// 1024-thread blocks, 16 waves each, one wave per row -> 512 WGs (4x fewer
// dispatches than R6; tests the dispatch-ramp theory behind Occupancy=69%).
// Cross-block traffic is device-scope atomic RMWs only (no fences); the
// completion-counter add is data-dependent on the bin RMW results.
__global__ __launch_bounds__(1024) void cosim_fused(const float* __restrict__ q,
                                                    const float* __restrict__ a,
                                                    const int* __restrict__ label,
                                                    const float* __restrict__ margin,
                                                    float* __restrict__ tbin,
                                                    float* __restrict__ fbin,
                                                    unsigned* __restrict__ tcb,
                                                    unsigned* __restrict__ fcb,
                                                    unsigned* __restrict__ counter,
                                                    float* __restrict__ out) {
    const int t    = threadIdx.x;
    const int lane = t & 63;
    const int wave = t >> 6;                 // 0..15
    const int row  = blockIdx.x * 16 + wave;

    const f32x4* q4 = reinterpret_cast<const f32x4*>(q + (size_t)row * D_DIM);
    const f32x4* a4 = reinterpret_cast<const f32x4*>(a + (size_t)row * D_DIM);

    float dot = 0.f, qq = 0.f, aa = 0.f;
#pragma unroll
    for (int k = 0; k < 16; ++k) {
        f32x4 vq = q4[lane + k * 64];
        f32x4 va = a4[lane + k * 64];
        dot += vq.x * va.x + vq.y * va.y + vq.z * va.z + vq.w * va.w;
        qq  += vq.x * vq.x + vq.y * vq.y + vq.z * vq.z + vq.w * vq.w;
        aa  += va.x * va.x + va.y * va.y + va.z * va.z + va.w * va.w;
    }

#pragma unroll
    for (int off = 32; off > 0; off >>= 1) {
        dot += __shfl_down(dot, off, 64);
        qq  += __shfl_down(qq,  off, 64);
        aa  += __shfl_down(aa,  off, 64);
    }

    __shared__ float    sh_t[16], sh_f[16];
    __shared__ unsigned sh_tc[16], sh_fc[16];
    __shared__ unsigned sh_prev;

    if (lane == 0) {
        float qn = fmaxf(sqrtf(qq), EPSF);
        float an = fmaxf(sqrtf(aa), EPSF);
        float c  = dot / (qn * an);
        int l = label[row];
        sh_t[wave]  = (l == 1)  ? c : 0.f;
        sh_f[wave]  = (l == -1) ? c : 0.f;
        sh_tc[wave] = (l == 1)  ? 1u : 0u;
        sh_fc[wave] = (l == -1) ? 1u : 0u;
    }
    __syncthreads();

    if (t == 0) {
        float ts = 0.f, fs = 0.f;
        unsigned tc = 0u, fc = 0u;
#pragma unroll
        for (int w = 0; w < 16; ++w) {
            ts += sh_t[w];  fs += sh_f[w];
            tc += sh_tc[w]; fc += sh_fc[w];
        }
        const int b = blockIdx.x & (NBINS - 1);
        float    o1 = atomicAdd(&tbin[b], ts);
        float    o2 = atomicAdd(&fbin[b], fs);
        unsigned o3 = atomicAdd(&tcb[b], tc);
        unsigned o4 = atomicAdd(&fcb[b], fc);
        // dep == 0 always, opaque to the compiler: counter RMW is issued only
        // after the bin RMW responses arrive (ordering without fences).
        unsigned dep = __float_as_uint(o1) | __float_as_uint(o2) | o3 | o4;
        asm volatile("v_and_b32 %0, 0, %0" : "+v"(dep));
        sh_prev = atomicAdd(counter, 1u + dep);
    }
    __syncthreads();

    if (sh_prev == (unsigned)(gridDim.x - 1)) {
        float    tb = 0.f, fb = 0.f;
        unsigned tcv = 0u, fcv = 0u;
        if (t < NBINS) {
            tb  = atomicAdd(&tbin[t], 0.f);
            fb  = atomicAdd(&fbin[t], 0.f);
            tcv = atomicAdd(&tcb[t], 0u);
            fcv = atomicAdd(&fcb[t], 0u);
        }
        if (wave == 0) {
#pragma unroll
            for (int off = 32; off > 0; off >>= 1) {
                tb  += __shfl_down(tb,  off, 64);
                fb  += __shfl_down(fb,  off, 64);
                tcv += __shfl_down(tcv, off, 64);
                fcv += __shfl_down(fcv, off, 64);
            }
            if (t == 0) {
                float true_ave  = tb / (float)tcv;
                float false_ave = fb / (float)fcv;
                out[0] = fmaxf(0.f, margin[0] - true_ave + false_ave);
            }
        }
    }
}

extern "C" void kernel_launch(void* const* d_in, const int* in_sizes, int n_in,
                              void* d_out, int out_size, void* d_ws, size_t ws_size,
                              hipStream_t stream) {
    const float* ques   = (const float*)d_in[0];
    const float* ans    = (const float*)d_in[1];
    const int*   label  = (const int*)d_in[2];
    const float* margin = (const float*)d_in[3];
    float* out = (float*)d_out;

    const int B = in_sizes[2];                          // 8192 rows
    float*    tbin    = (float*)d_ws;                   // 64 floats
    float*    fbin    = (float*)((char*)d_ws + 256);    // 64 floats
    unsigned* tcb     = (unsigned*)((char*)d_ws + 512); // 64 uints
    unsigned* fcb     = (unsigned*)((char*)d_ws + 768); // 64 uints
    unsigned* counter = (unsigned*)((char*)d_ws + 1024);

    hipMemsetAsync(d_ws, 0, 1056, stream);
    // 1 wave per row, 16 rows per 1024-thread block -> B/16 = 512 blocks
    cosim_fused<<<B / 16, 1024, 0, stream>>>(ques, ans, label, margin,
                                             tbin, fbin, tcb, fcb, counter, out);
}